// Round 17
// baseline (89.618 us; speedup 1.0000x reference)
//
#include <hip/hip_runtime.h>
#include <hip/hip_bf16.h>
#include <hip/hip_fp16.h>
#include <cstdint>
#include <cstddef>

#define T_SEQ 2048
#define NBATCH 2
#define DIMD 512
#define NH 8
#define NS 16
#define HD 64
#define NBH 16

using s16x8 = __attribute__((ext_vector_type(8))) short;
using f32x4 = __attribute__((ext_vector_type(4))) float;

static __device__ inline unsigned short f2bf(float f) {
  __hip_bfloat16 h = __float2bfloat16(f);
  return reinterpret_cast<unsigned short&>(h);
}
static __device__ inline unsigned short f2h(float f) {
  __half h = __float2half(f);
  return reinterpret_cast<unsigned short&>(h);
}
static __device__ inline float h2f(unsigned short u) {
  __half h = reinterpret_cast<__half&>(u);
  return __half2float(h);
}
static __device__ inline unsigned int pack2(float a, float b) {
  return (unsigned int)f2bf(a) | ((unsigned int)f2bf(b) << 16);
}
static __device__ inline void gload16(const void* g, void* l) {
  __builtin_amdgcn_global_load_lds((const __attribute__((address_space(1))) void*)g,
                                   (__attribute__((address_space(3))) void*)l, 16, 0, 0);
}
// bijective XCD swizzle (nwg % 8 == 0)
static __device__ inline int swz_id() {
  int nwg = gridDim.x * gridDim.y;
  int orig = blockIdx.y * gridDim.x + blockIdx.x;
  return (orig & 7) * (nwg >> 3) + (orig >> 3);
}

// ---- workspace layout (float offsets) ----
static const size_t OFF_VBUF = 0;         // 4096x512 fp16 v
static const size_t OFF_AOUT = 2097152;   // 4096x512 fp16 attn-out
static const size_t OFF_XH   = 6291456;   // fp16 x (4MB); later aliased by vt (bf16 4MB)
static const size_t OFF_WQH  = 8388608;   // fp16 Wqkv
static const size_t OFF_WOH  = 9175040;   // fp16 Wout
static const size_t OFF_QABF = 9437184;   // 16x2048x32 bf16, PLAIN layout
static const size_t OFF_KWBF = 9961472;   // 16x2048x32 bf16, slot-swizzled
static const size_t OFF_SPART= 10485760;  // [4][16][2048] f32 partial colsums
static const size_t OFF_VPART= 10616832;  // [16][16][64] f32
static const size_t OFF_CADJ = 10633216;
static const size_t OFF_IVAR = 10641408;
static const size_t OFF_AMPT = 10641536;

// ------------------- PREP: params + fp32->fp16 conversions
__global__ __launch_bounds__(256) void prep(
    const float* __restrict__ x, const float* __restrict__ Wqkv, const float* __restrict__ Wout,
    const float* __restrict__ centers, const float* __restrict__ deltas,
    const float* __restrict__ lsc, const float* __restrict__ lam,
    const float* __restrict__ ms, const float* __restrict__ tp,
    unsigned short* __restrict__ xh, unsigned short* __restrict__ wqh,
    unsigned short* __restrict__ woh,
    float* __restrict__ cadj, float* __restrict__ ivar, float* __restrict__ ampt) {
  int bid = blockIdx.x;
  int tid = threadIdx.x;
  if (bid == 3072) {
    float bscale = 0.2f / (1.0f + expf(-ms[0]));
    float tclip = fminf(fmaxf(tp[0], 0.1f), 10.0f);
    if (tid < NH * NS) {
      float sc = fminf(fmaxf(expf(lsc[tid]), 0.01f), 2.0f);
      ivar[tid] = 1.0f / (sc * sc + 1e-8f);
      float am = fminf(fmaxf(expf(lam[tid]), 1e-6f), 10.0f);
      am = (am > 0.02f) ? am : 0.0f;
      // fold 1/temp AND log2(e) into qa so logits feed exp2 directly
      ampt[tid] = (am / tclip) * 1.44269504088896340736f;
    }
    for (int e = tid; e < NH * NS * HD; e += 256)
      cadj[e] = centers[e] + deltas[e] * bscale;
    return;
  }
  const float* src; unsigned short* dh; int i4;
  if (bid < 2048)      { src = x;    dh = xh;  i4 = bid * 256 + tid; }
  else if (bid < 2816) { src = Wqkv; dh = wqh; i4 = (bid - 2048) * 256 + tid; }
  else                 { src = Wout; dh = woh; i4 = (bid - 2816) * 256 + tid; }
  float4 v = *(const float4*)&src[(size_t)i4 * 4];
  ushort4 hh;
  hh.x = f2h(v.x); hh.y = f2h(v.y); hh.z = f2h(v.z); hh.w = f2h(v.w);
  *(ushort4*)&dh[(size_t)i4 * 4] = hh;
}

// ---- fp16 1-pass MFMA GEMM core, BK=64, swizzled LDS rows; acc in registers
template<int BM, int BN>
__device__ __forceinline__ void gemm_core(
    const unsigned short* Ah, const unsigned short* Bh,
    int K, int m0, int n0,
    unsigned short* ash, unsigned short* bsh,
    f32x4 (&acc)[BM / 32][BN / 32]) {
  constexpr int WM = BM / 2, WN = BN / 2;
  constexpr int MF = WM / 16, NF = WN / 16;
  constexpr int NSA = BM / 8, NSB = BN / 8;
  constexpr int TSEG = NSA + NSB;
  int tid = threadIdx.x;
  int w = tid >> 6, l = tid & 63, lm = l & 15, lq = l >> 4;
  int wm = w >> 1, wn = w & 1;
  int r8 = l >> 3, c8 = l & 7;
  int ksl = (c8 ^ (r8 & 7)) << 3;
#pragma unroll
  for (int mi = 0; mi < MF; ++mi)
#pragma unroll
    for (int ni = 0; ni < NF; ++ni) acc[mi][ni] = (f32x4){0.f, 0.f, 0.f, 0.f};

  for (int k0 = 0; k0 < K; k0 += 64) {
    __syncthreads();
#pragma unroll
    for (int t = 0; t < TSEG / 4; ++t) {
      int s = w + t * 4;
      if (s < NSA) {
        gload16(&Ah[(size_t)(m0 + s * 8 + r8) * K + k0 + ksl], &ash[s * 512]);
      } else {
        int ss = s - NSA;
        gload16(&Bh[(size_t)(n0 + ss * 8 + r8) * K + k0 + ksl], &bsh[ss * 512]);
      }
    }
    __syncthreads();
#pragma unroll
    for (int kh = 0; kh < 2; ++kh) {
      s16x8 fah[MF], fbh[NF];
#pragma unroll
      for (int mi = 0; mi < MF; ++mi) {
        int rr = wm * WM + mi * 16 + lm;
        int off = rr * 64 + ((((kh << 2) | lq) ^ (rr & 7)) << 3);
        fah[mi] = *(const s16x8*)&ash[off];
      }
#pragma unroll
      for (int ni = 0; ni < NF; ++ni) {
        int cc = wn * WN + ni * 16 + lm;
        int off = cc * 64 + ((((kh << 2) | lq) ^ (cc & 7)) << 3);
        fbh[ni] = *(const s16x8*)&bsh[off];
      }
#pragma unroll
      for (int mi = 0; mi < MF; ++mi)
#pragma unroll
        for (int ni = 0; ni < NF; ++ni)
          acc[mi][ni] = __builtin_amdgcn_mfma_f32_16x16x32_f16(fah[mi], fbh[ni], acc[mi][ni], 0, 0, 0);
    }
  }
}

template<int BM, int BN>
__device__ __forceinline__ void write_c(
    float* C, int ldc, int m0, int n0, f32x4 (&acc)[BM / 32][BN / 32]) {
  constexpr int WM = BM / 2, WN = BN / 2;
  int tid = threadIdx.x;
  int w = tid >> 6, l = tid & 63, lm = l & 15, lq = l >> 4;
  int wm = w >> 1, wn = w & 1;
#pragma unroll
  for (int mi = 0; mi < BM / 32; ++mi)
#pragma unroll
    for (int ni = 0; ni < BN / 32; ++ni)
#pragma unroll
      for (int r = 0; r < 4; ++r) {
        int row = m0 + wm * WM + mi * 16 + lq * 4 + r;
        int col = n0 + wn * WN + ni * 16 + lm;
        C[(size_t)row * ldc + col] = acc[mi][ni][r];
      }
}

template<int BM, int BN>
__device__ __forceinline__ void write_ch(
    unsigned short* C, int ldc, int m0, int n0, f32x4 (&acc)[BM / 32][BN / 32]) {
  constexpr int WM = BM / 2, WN = BN / 2;
  int tid = threadIdx.x;
  int w = tid >> 6, l = tid & 63, lm = l & 15, lq = l >> 4;
  int wm = w >> 1, wn = w & 1;
#pragma unroll
  for (int mi = 0; mi < BM / 32; ++mi)
#pragma unroll
    for (int ni = 0; ni < BN / 32; ++ni)
#pragma unroll
      for (int r = 0; r < 4; ++r) {
        int row = m0 + wm * WM + mi * 16 + lq * 4 + r;
        int col = n0 + wn * WN + ni * 16 + lm;
        C[(size_t)row * ldc + col] = f2h(acc[mi][ni][r]);
      }
}

// qkv GEMM (fp16, 1-pass) + fused splat features.
// bx 0..7: q head bx -> qa; bx 8..15: k head bx-8 -> kw; bx 16..23: v -> vbuf (fp16).
__global__ __launch_bounds__(256) void gemm_qkv(
    const unsigned short* __restrict__ xh, const unsigned short* __restrict__ wqh,
    const float* __restrict__ cadj, const float* __restrict__ ivar,
    const float* __restrict__ ampt, unsigned short* __restrict__ vbuf,
    unsigned short* __restrict__ qa_bf, unsigned short* __restrict__ kw_bf) {
  __shared__ __align__(16) char smem[39168];
  unsigned short* ash = (unsigned short*)smem;            // 16KB
  unsigned short* bsh = (unsigned short*)(smem + 16384);  // 8KB
  int sid = swz_id();
  int bx = sid % 24, by = sid / 24;
  int m0 = by * 128;
  int tid = threadIdx.x;
  f32x4 acc[4][2];
  if (bx >= 16) {
    gemm_core<128, 64>(xh, wqh + (size_t)(1024 + (bx - 16) * 64) * 512,
                       512, m0, 0, ash, bsh, acc);
    write_ch<128, 64>(vbuf, 512, m0, (bx - 16) * 64, acc);
    return;
  }
  bool isk = bx >= 8;
  int h = bx & 7;
  gemm_core<128, 64>(xh, wqh + (size_t)((isk ? 512 : 0) + h * 64) * 512,
                     512, m0, 0, ash, bsh, acc);
  // ---- fused feature epilogue (exact fp32 q/k from accumulators) ----
  __syncthreads();                          // staging LDS dead
  float* q_s = (float*)smem;                // [128][68] = 34816B
  float* c_s = (float*)(smem + 34816);      // [16][68]  = 4352B
  {
    int w = tid >> 6, l = tid & 63, lm = l & 15, lq = l >> 4;
    int wm = w >> 1, wn = w & 1;
#pragma unroll
    for (int mi = 0; mi < 4; ++mi)
#pragma unroll
      for (int ni = 0; ni < 2; ++ni)
#pragma unroll
        for (int r = 0; r < 4; ++r)
          q_s[(wm * 64 + mi * 16 + lq * 4 + r) * 68 + wn * 32 + ni * 16 + lm] = acc[mi][ni][r];
    int cr = tid >> 4, d4 = tid & 15;
    *(float4*)&c_s[cr * 68 + d4 * 4] = *(const float4*)&cadj[(h * 16 + cr) * 64 + d4 * 4];
  }
  __syncthreads();
  int s = tid & 15, rbase = tid >> 4;
  float iv = ivar[h * 16 + s];
  float am = ampt[h * 16 + s];
  const float4* crow = (const float4*)&c_s[s * 68];
#pragma unroll
  for (int t = 0; t < 8; ++t) {
    int r = t * 16 + rbase;
    const float4* qrow = (const float4*)&q_s[r * 68];
    float d2 = 0.0f;
#pragma unroll
    for (int d4 = 0; d4 < 16; ++d4) {
      float4 qv = qrow[d4], cv = crow[d4];
      float e0 = qv.x - cv.x, e1 = qv.y - cv.y, e2 = qv.z - cv.z, e3 = qv.w - cv.w;
      d2 = fmaf(e0, e0, d2); d2 = fmaf(e1, e1, d2);
      d2 = fmaf(e2, e2, d2); d2 = fmaf(e3, e3, d2);
    }
    float val = __expf(-0.5f * d2 * iv);
    int row = m0 + r;                       // global row = b*2048 + i
    int b = row >> 11, i = row & 2047;
    size_t base = ((size_t)(b * 8 + h) * T_SEQ + i) * 32;
    if (!isk) {
      qa_bf[base + s] = f2bf(val * am);
      qa_bf[base + 16 + s] = 0;
    } else {
      int xorv = (r >> 1) & 3;
      int slot = s >> 3, e = s & 7;
      kw_bf[base + (size_t)((slot ^ xorv) << 3) + e] = f2bf(val);
      kw_bf[base + (size_t)(((2 + slot) ^ xorv) << 3) + e] = 0;
    }
  }
}

// output GEMM: fp16 aout x fp16 Wout, 64x64 tile
__global__ __launch_bounds__(256) void gemm_out(
    const unsigned short* __restrict__ aout_h, const unsigned short* __restrict__ woh,
    float* __restrict__ out) {
  __shared__ __align__(16) unsigned short ash[64 * 64];
  __shared__ __align__(16) unsigned short bsh[64 * 64];
  int sid = swz_id();
  int bx = sid % 8, by = sid / 8;
  f32x4 acc[2][2];
  gemm_core<64, 64>(aout_h + (size_t)by * 64 * 512, woh + (size_t)bx * 64 * 512,
                    512, 0, 0, ash, bsh, acc);
  write_c<64, 64>(out, 512, by * 64, bx * 64, acc);
}

// --------------------------- K3: spart[iq][bh][j] = sum_{i in quarter} expm1_2(l_ij)
__global__ __launch_bounds__(256) void k3_colsum(
    const unsigned short* __restrict__ qa_bf, const unsigned short* __restrict__ kw_bf,
    float* __restrict__ spart) {
  int sid = swz_id();                        // grid (16, 64)
  int jblk = sid & 15, yy = sid >> 4;
  int bh = yy >> 2, iq = yy & 3;
  int tid = threadIdx.x;
  int w = tid >> 6, l = tid & 63, lm = l & 15, lq = l >> 4;
  int jbase = (jblk << 7) + (w << 5);
  int sw = lq ^ ((lm >> 1) & 3);
  size_t base32 = (size_t)bh * T_SEQ * 32;
  s16x8 kwB0 = *(const s16x8*)&kw_bf[base32 + (size_t)(jbase + lm) * 32 + sw * 8];
  s16x8 kwB1 = *(const s16x8*)&kw_bf[base32 + (size_t)(jbase + 16 + lm) * 32 + sw * 8];
  const unsigned short* qp = qa_bf + base32 + ((size_t)(iq * 512) + lm) * 32 + lq * 8;
  float s0 = 0.0f, s1 = 0.0f;
  f32x4 z = (f32x4){0.f, 0.f, 0.f, 0.f};
#pragma unroll 4
  for (int it = 0; it < 512; it += 16) {
    s16x8 qaA = *(const s16x8*)(qp + (size_t)it * 32);
    f32x4 L0 = __builtin_amdgcn_mfma_f32_16x16x32_bf16(qaA, kwB0, z, 0, 0, 0);
    f32x4 L1 = __builtin_amdgcn_mfma_f32_16x16x32_bf16(qaA, kwB1, z, 0, 0, 0);
    s0 += (exp2f(L0[0]) - 1.0f) + (exp2f(L0[1]) - 1.0f)
        + (exp2f(L0[2]) - 1.0f) + (exp2f(L0[3]) - 1.0f);
    s1 += (exp2f(L1[0]) - 1.0f) + (exp2f(L1[1]) - 1.0f)
        + (exp2f(L1[2]) - 1.0f) + (exp2f(L1[3]) - 1.0f);
  }
  s0 += __shfl_xor(s0, 16); s0 += __shfl_xor(s0, 32);
  s1 += __shfl_xor(s1, 16); s1 += __shfl_xor(s1, 32);
  if (l < 16) {
    float* sp = spart + ((size_t)iq * NBH + bh) * T_SEQ;
    sp[jbase + lm] = s0;
    sp[jbase + 16 + lm] = s1;
  }
}

// ------------- K3c: sinv inline; vt[bh][d][j_sw] = bf16(v*sinv); vpart stripes
__global__ __launch_bounds__(256) void k3c_vt(
    const unsigned short* __restrict__ vbuf, const float* __restrict__ spart,
    unsigned short* __restrict__ vt, float* __restrict__ vpart) {
  int bh = blockIdx.y; int b = bh >> 3, h = bh & 7;
  int js = blockIdx.x << 7;                  // 128 j per block
  int tid = threadIdx.x;
  __shared__ unsigned short t_s[64][136];
  __shared__ float red[16][64];
  int jg = tid >> 4, dq = tid & 15;
  const unsigned short* vb = vbuf + (size_t)b * T_SEQ * 512 + h * 64;
  const float* sp0 = spart + (size_t)bh * T_SEQ + js;
  const float* sp1 = spart + ((size_t)NBH + bh) * T_SEQ + js;
  const float* sp2 = spart + ((size_t)2 * NBH + bh) * T_SEQ + js;
  const float* sp3 = spart + ((size_t)3 * NBH + bh) * T_SEQ + js;
  float a0 = 0.f, a1 = 0.f, a2 = 0.f, a3 = 0.f;
#pragma unroll
  for (int p = 0; p < 8; ++p) {
    int j = p * 16 + jg;
    float s = 1.0f / (2048.0f + sp0[j] + sp1[j] + sp2[j] + sp3[j]);
    ushort4 vu = *(const ushort4*)&vb[(size_t)(js + j) * 512 + dq * 4];
    float v0 = h2f(vu.x) * s, v1 = h2f(vu.y) * s, v2 = h2f(vu.z) * s, v3 = h2f(vu.w) * s;
    t_s[dq * 4 + 0][j] = f2bf(v0);
    t_s[dq * 4 + 1][j] = f2bf(v1);
    t_s[dq * 4 + 2][j] = f2bf(v2);
    t_s[dq * 4 + 3][j] = f2bf(v3);
    a0 += v0; a1 += v1; a2 += v2; a3 += v3;
  }
  red[jg][dq * 4 + 0] = a0; red[jg][dq * 4 + 1] = a1;
  red[jg][dq * 4 + 2] = a2; red[jg][dq * 4 + 3] = a3;
  __syncthreads();
  if (tid < 64) {
    float t = 0.f;
#pragma unroll
    for (int g = 0; g < 16; ++g) t += red[g][tid];
    vpart[((size_t)blockIdx.x * NBH + bh) * 64 + tid] = t;
  }
#pragma unroll
  for (int p = 0; p < 4; ++p) {
    int idx = p * 256 + tid;
    int d = idx >> 4, seg = idx & 15;
    int4 val = *(const int4*)&t_s[d][seg * 8];
    int col = ((seg >> 3) << 6) + ((((seg & 7) ^ (d & 7))) << 3);
    *(int4*)&vt[(size_t)bh * 131072 + (size_t)d * 2048 + js + col] = val;
  }
}

// ------------- K4: aout = vsum + sum_j expm1_2(l_ij) * vt[j]
// 128-i blocks, 16 waves = 4 ig (32 i, 2 i-frags) x 4 jq (512 j each).
// In-register P->pA; 4-way LDS merge.
__global__ __launch_bounds__(1024) void k4_attnout(
    const unsigned short* __restrict__ qa_bf, const unsigned short* __restrict__ kw_bf,
    const unsigned short* __restrict__ vt, const float* __restrict__ vpart,
    unsigned short* __restrict__ aout_h) {
  int sid = swz_id();                        // grid (16 i-blocks, 16 bh)
  int bh = sid >> 4; int b = bh >> 3, h = bh & 7;
  int i0 = (sid & 15) << 7;                  // 128 rows per block
  int tid = threadIdx.x;
  int w = tid >> 6, l = tid & 63, lm = l & 15, lq = l >> 4;
  int ig = w >> 2, jq = w & 3;               // ig 0..3 (32 i each), jq 0..3 (512 j each)
  __shared__ __align__(16) char smem[98304];
  unsigned short* kwS = (unsigned short*)smem;             // [4][2][2048] = 32KB
  unsigned short* vtS = (unsigned short*)(smem + 32768);   // [4][2][4096] = 64KB
  float* mrg = (float*)smem;                               // 24576 f = 96KB (post-loop)
  const unsigned short* kwg = kw_bf + (size_t)bh * (T_SEQ * 32) + (size_t)jq * (512 * 32);
  const unsigned short* vtg = vt + (size_t)bh * 131072 + jq * 512;
  // kw row permutation for in-register pA
  int p0 = ((lm >> 2) << 3) | (lm & 3);
  int sw0 = lq ^ ((lm >> 1) & 1);
  int sw1 = sw0 ^ 2;
  int swv = lm & 7;
  s16x8 qaB0 = *(const s16x8*)&qa_bf[((size_t)bh * T_SEQ + i0 + ig * 32 + lm) * 32 + lq * 8];
  s16x8 qaB1 = *(const s16x8*)&qa_bf[((size_t)bh * T_SEQ + i0 + ig * 32 + 16 + lm) * 32 + lq * 8];
  f32x4 acc[2][4];
#pragma unroll
  for (int ifr = 0; ifr < 2; ++ifr)
#pragma unroll
    for (int df = 0; df < 4; ++df) acc[ifr][df] = (f32x4){0.f, 0.f, 0.f, 0.f};
  f32x4 z = (f32x4){0.f, 0.f, 0.f, 0.f};

  auto stage = [&](int c, int bsel) {
#pragma unroll
    for (int t = 0; t < 2; ++t) {
      int li = ig * 2 + t;
      gload16(&vtg[(size_t)(li * 8 + (l >> 3)) * 2048 + c * 64 + (l & 7) * 8],
              &vtS[(jq * 2 + bsel) * 4096 + li * 512]);
    }
    gload16(&kwg[(size_t)(c * 64 + ig * 16 + (l >> 2)) * 32 + (l & 3) * 8],
            &kwS[(jq * 2 + bsel) * 2048 + ig * 512]);
  };

  stage(0, 0);
  __syncthreads();
  for (int c = 0; c < 8; ++c) {
    int bsel = c & 1;
    if (c < 7) stage(c + 1, bsel ^ 1);
    const unsigned short* kwb = &kwS[(jq * 2 + bsel) * 2048];
    const unsigned short* vtb = &vtS[(jq * 2 + bsel) * 4096];
#pragma unroll
    for (int s = 0; s < 2; ++s) {
      s16x8 ka0 = *(const s16x8*)&kwb[(s * 32 + p0) * 32 + sw0 * 8];
      s16x8 ka1 = *(const s16x8*)&kwb[(s * 32 + p0 + 4) * 32 + sw1 * 8];
      s16x8 vb0 = *(const s16x8*)&vtb[(size_t)(0 + lm) * 64 + (((4 * s + lq) ^ swv) << 3)];
      s16x8 vb1 = *(const s16x8*)&vtb[(size_t)(16 + lm) * 64 + (((4 * s + lq) ^ swv) << 3)];
      s16x8 vb2 = *(const s16x8*)&vtb[(size_t)(32 + lm) * 64 + (((4 * s + lq) ^ swv) << 3)];
      s16x8 vb3 = *(const s16x8*)&vtb[(size_t)(48 + lm) * 64 + (((4 * s + lq) ^ swv) << 3)];
#pragma unroll
      for (int ifr = 0; ifr < 2; ++ifr) {
        s16x8 qaB = ifr ? qaB1 : qaB0;
        f32x4 L0 = __builtin_amdgcn_mfma_f32_16x16x32_bf16(ka0, qaB, z, 0, 0, 0);
        f32x4 L1 = __builtin_amdgcn_mfma_f32_16x16x32_bf16(ka1, qaB, z, 0, 0, 0);
        union { unsigned int u4[4]; s16x8 v; } cvt;
        cvt.u4[0] = pack2(exp2f(L0[0]) - 1.0f, exp2f(L0[1]) - 1.0f);
        cvt.u4[1] = pack2(exp2f(L0[2]) - 1.0f, exp2f(L0[3]) - 1.0f);
        cvt.u4[2] = pack2(exp2f(L1[0]) - 1.0f, exp2f(L1[1]) - 1.0f);
        cvt.u4[3] = pack2(exp2f(L1[2]) - 1.0f, exp2f(L1[3]) - 1.0f);
        s16x8 pA = cvt.v;
        __builtin_amdgcn_s_setprio(1);
        acc[ifr][0] = __builtin_amdgcn_mfma_f32_16x16x32_bf16(pA, vb0, acc[ifr][0], 0, 0, 0);
        acc[ifr][1] = __builtin_amdgcn_mfma_f32_16x16x32_bf16(pA, vb1, acc[ifr][1], 0, 0, 0);
        acc[ifr][2] = __builtin_amdgcn_mfma_f32_16x16x32_bf16(pA, vb2, acc[ifr][2], 0, 0, 0);
        acc[ifr][3] = __builtin_amdgcn_mfma_f32_16x16x32_bf16(pA, vb3, acc[ifr][3], 0, 0, 0);
        __builtin_amdgcn_s_setprio(0);
      }
    }
    __syncthreads();
  }
  // 4-way merge across jq via LDS (reuse full 96KB smem), jq=0 waves write out
  if (jq != 0) {
    int base = ((jq - 1) * 4 + ig) * 2;
#pragma unroll
    for (int ifr = 0; ifr < 2; ++ifr)
#pragma unroll
      for (int df = 0; df < 4; ++df)
#pragma unroll
        for (int r = 0; r < 4; ++r)
          mrg[(((base + ifr) * 4 + df) * 4 + r) * 64 + l] = acc[ifr][df][r];
  }
  __syncthreads();
  if (jq == 0) {
#pragma unroll
    for (int ifr = 0; ifr < 2; ++ifr)
#pragma unroll
      for (int df = 0; df < 4; ++df) {
        int d = df * 16 + lm;
        float vs = 0.0f;
#pragma unroll
        for (int js = 0; js < 16; ++js) vs += vpart[((size_t)js * NBH + bh) * 64 + d];
#pragma unroll
        for (int r = 0; r < 4; ++r) {
          int row = i0 + ig * 32 + ifr * 16 + lq * 4 + r;
          float o = acc[ifr][df][r] + vs;
#pragma unroll
          for (int jm = 0; jm < 3; ++jm)
            o += mrg[((((jm * 4 + ig) * 2 + ifr) * 4 + df) * 4 + r) * 64 + l];
          aout_h[((size_t)b * T_SEQ + row) * DIMD + h * 64 + d] = f2h(o);
        }
      }
  }
}

// ----------------------------------------------------------------------------
extern "C" void kernel_launch(void* const* d_in, const int* in_sizes, int n_in,
                              void* d_out, int out_size, void* d_ws, size_t ws_size,
                              hipStream_t stream) {
  const float* x    = (const float*)d_in[0];
  const float* Wqkv = (const float*)d_in[1];
  const float* Wout = (const float*)d_in[2];
  const float* ctr  = (const float*)d_in[3];
  const float* dlt  = (const float*)d_in[4];
  const float* lsc  = (const float*)d_in[5];
  const float* lam  = (const float*)d_in[6];
  const float* ms   = (const float*)d_in[7];
  const float* tp   = (const float*)d_in[8];
  float* ws = (float*)d_ws;
  unsigned short* vbuf   = (unsigned short*)(ws + OFF_VBUF);   // fp16
  unsigned short* aout_h = (unsigned short*)(ws + OFF_AOUT);   // fp16
  unsigned short* xh  = (unsigned short*)(ws + OFF_XH);        // fp16
  unsigned short* wqh = (unsigned short*)(ws + OFF_WQH);       // fp16
  unsigned short* woh = (unsigned short*)(ws + OFF_WOH);       // fp16
  unsigned short* qa_bf = (unsigned short*)(ws + OFF_QABF);
  unsigned short* kw_bf = (unsigned short*)(ws + OFF_KWBF);
  float* spart = ws + OFF_SPART;
  float* vpart = ws + OFF_VPART;
  float* cadj  = ws + OFF_CADJ;
  float* ivar  = ws + OFF_IVAR;
  float* ampt  = ws + OFF_AMPT;
  unsigned short* vt = xh;                 // bf16 vt aliases xh (dead after gemm_qkv)
  float* out = (float*)d_out;

  prep<<<3073, 256, 0, stream>>>(x, Wqkv, Wout, ctr, dlt, lsc, lam, ms, tp,
                                 xh, wqh, woh, cadj, ivar, ampt);
  gemm_qkv<<<dim3(24, 32), 256, 0, stream>>>(xh, wqh, cadj, ivar, ampt,
                                             vbuf, qa_bf, kw_bf);
  k3_colsum<<<dim3(16, 64), 256, 0, stream>>>(qa_bf, kw_bf, spart);
  k3c_vt<<<dim3(16, 16), 256, 0, stream>>>(vbuf, spart, vt, vpart);
  k4_attnout<<<dim3(16, 16), 1024, 0, stream>>>(qa_bf, kw_bf, vt, vpart, aout_h);
  gemm_out<<<dim3(8, 64), 256, 0, stream>>>(aout_h, woh, out);
}

// Round 18
// 75.327 us; speedup vs baseline: 1.1897x; 1.1897x over previous
//
#include <hip/hip_runtime.h>
#include <hip/hip_bf16.h>
#include <hip/hip_fp16.h>
#include <cstdint>
#include <cstddef>

#define T_SEQ 2048
#define NBATCH 2
#define DIMD 512
#define NH 8
#define NS 16
#define HD 64
#define NBH 16

using s16x8 = __attribute__((ext_vector_type(8))) short;
using f32x4 = __attribute__((ext_vector_type(4))) float;

static __device__ inline unsigned short f2bf(float f) {
  __hip_bfloat16 h = __float2bfloat16(f);
  return reinterpret_cast<unsigned short&>(h);
}
static __device__ inline unsigned short f2h(float f) {
  __half h = __float2half(f);
  return reinterpret_cast<unsigned short&>(h);
}
static __device__ inline float h2f(unsigned short u) {
  __half h = reinterpret_cast<__half&>(u);
  return __half2float(h);
}
static __device__ inline unsigned int pack2(float a, float b) {
  return (unsigned int)f2bf(a) | ((unsigned int)f2bf(b) << 16);
}
static __device__ inline float fexp2(float x) {
  return __builtin_amdgcn_exp2f(x);          // bare v_exp_f32 (2^x)
}
static __device__ inline void gload16(const void* g, void* l) {
  __builtin_amdgcn_global_load_lds((const __attribute__((address_space(1))) void*)g,
                                   (__attribute__((address_space(3))) void*)l, 16, 0, 0);
}
// bijective XCD swizzle (nwg % 8 == 0)
static __device__ inline int swz_id() {
  int nwg = gridDim.x * gridDim.y;
  int orig = blockIdx.y * gridDim.x + blockIdx.x;
  return (orig & 7) * (nwg >> 3) + (orig >> 3);
}

// ---- workspace layout (float offsets) ----
static const size_t OFF_VBUF = 0;         // 4096x512 fp16 v
static const size_t OFF_AOUT = 2097152;   // 4096x512 fp16 attn-out
static const size_t OFF_XH   = 6291456;   // fp16 x (4MB); later aliased by vt (bf16 4MB)
static const size_t OFF_WQH  = 8388608;   // fp16 Wqkv
static const size_t OFF_WOH  = 9175040;   // fp16 Wout
static const size_t OFF_QABF = 9437184;   // 16x2048x32 bf16, PLAIN layout
static const size_t OFF_KWBF = 9961472;   // 16x2048x32 bf16, slot-swizzled
static const size_t OFF_SPART= 10485760;  // [4][16][2048] f32 partial colsums
static const size_t OFF_VPART= 10616832;  // [16][16][64] f32
static const size_t OFF_CADJ = 10633216;
static const size_t OFF_IVAR = 10641408;
static const size_t OFF_AMPT = 10641536;

// ------------------- PREP: params + fp32->fp16 conversions
__global__ __launch_bounds__(256) void prep(
    const float* __restrict__ x, const float* __restrict__ Wqkv, const float* __restrict__ Wout,
    const float* __restrict__ centers, const float* __restrict__ deltas,
    const float* __restrict__ lsc, const float* __restrict__ lam,
    const float* __restrict__ ms, const float* __restrict__ tp,
    unsigned short* __restrict__ xh, unsigned short* __restrict__ wqh,
    unsigned short* __restrict__ woh,
    float* __restrict__ cadj, float* __restrict__ ivar, float* __restrict__ ampt) {
  int bid = blockIdx.x;
  int tid = threadIdx.x;
  if (bid == 3072) {
    float bscale = 0.2f / (1.0f + expf(-ms[0]));
    float tclip = fminf(fmaxf(tp[0], 0.1f), 10.0f);
    if (tid < NH * NS) {
      float sc = fminf(fmaxf(expf(lsc[tid]), 0.01f), 2.0f);
      ivar[tid] = 1.0f / (sc * sc + 1e-8f);
      float am = fminf(fmaxf(expf(lam[tid]), 1e-6f), 10.0f);
      am = (am > 0.02f) ? am : 0.0f;
      // fold 1/temp AND log2(e) into qa so logits feed v_exp_f32 (2^x) directly
      ampt[tid] = (am / tclip) * 1.44269504088896340736f;
    }
    for (int e = tid; e < NH * NS * HD; e += 256)
      cadj[e] = centers[e] + deltas[e] * bscale;
    return;
  }
  const float* src; unsigned short* dh; int i4;
  if (bid < 2048)      { src = x;    dh = xh;  i4 = bid * 256 + tid; }
  else if (bid < 2816) { src = Wqkv; dh = wqh; i4 = (bid - 2048) * 256 + tid; }
  else                 { src = Wout; dh = woh; i4 = (bid - 2816) * 256 + tid; }
  float4 v = *(const float4*)&src[(size_t)i4 * 4];
  ushort4 hh;
  hh.x = f2h(v.x); hh.y = f2h(v.y); hh.z = f2h(v.z); hh.w = f2h(v.w);
  *(ushort4*)&dh[(size_t)i4 * 4] = hh;
}

// ---- fp16 1-pass MFMA GEMM core, BK=64, swizzled LDS rows; acc in registers
template<int BM, int BN>
__device__ __forceinline__ void gemm_core(
    const unsigned short* Ah, const unsigned short* Bh,
    int K, int m0, int n0,
    unsigned short* ash, unsigned short* bsh,
    f32x4 (&acc)[BM / 32][BN / 32]) {
  constexpr int WM = BM / 2, WN = BN / 2;
  constexpr int MF = WM / 16, NF = WN / 16;
  constexpr int NSA = BM / 8, NSB = BN / 8;
  constexpr int TSEG = NSA + NSB;
  int tid = threadIdx.x;
  int w = tid >> 6, l = tid & 63, lm = l & 15, lq = l >> 4;
  int wm = w >> 1, wn = w & 1;
  int r8 = l >> 3, c8 = l & 7;
  int ksl = (c8 ^ (r8 & 7)) << 3;
#pragma unroll
  for (int mi = 0; mi < MF; ++mi)
#pragma unroll
    for (int ni = 0; ni < NF; ++ni) acc[mi][ni] = (f32x4){0.f, 0.f, 0.f, 0.f};

  for (int k0 = 0; k0 < K; k0 += 64) {
    __syncthreads();
#pragma unroll
    for (int t = 0; t < TSEG / 4; ++t) {
      int s = w + t * 4;
      if (s < NSA) {
        gload16(&Ah[(size_t)(m0 + s * 8 + r8) * K + k0 + ksl], &ash[s * 512]);
      } else {
        int ss = s - NSA;
        gload16(&Bh[(size_t)(n0 + ss * 8 + r8) * K + k0 + ksl], &bsh[ss * 512]);
      }
    }
    __syncthreads();
#pragma unroll
    for (int kh = 0; kh < 2; ++kh) {
      s16x8 fah[MF], fbh[NF];
#pragma unroll
      for (int mi = 0; mi < MF; ++mi) {
        int rr = wm * WM + mi * 16 + lm;
        int off = rr * 64 + ((((kh << 2) | lq) ^ (rr & 7)) << 3);
        fah[mi] = *(const s16x8*)&ash[off];
      }
#pragma unroll
      for (int ni = 0; ni < NF; ++ni) {
        int cc = wn * WN + ni * 16 + lm;
        int off = cc * 64 + ((((kh << 2) | lq) ^ (cc & 7)) << 3);
        fbh[ni] = *(const s16x8*)&bsh[off];
      }
#pragma unroll
      for (int mi = 0; mi < MF; ++mi)
#pragma unroll
        for (int ni = 0; ni < NF; ++ni)
          acc[mi][ni] = __builtin_amdgcn_mfma_f32_16x16x32_f16(fah[mi], fbh[ni], acc[mi][ni], 0, 0, 0);
    }
  }
}

template<int BM, int BN>
__device__ __forceinline__ void write_c(
    float* C, int ldc, int m0, int n0, f32x4 (&acc)[BM / 32][BN / 32]) {
  constexpr int WM = BM / 2, WN = BN / 2;
  int tid = threadIdx.x;
  int w = tid >> 6, l = tid & 63, lm = l & 15, lq = l >> 4;
  int wm = w >> 1, wn = w & 1;
#pragma unroll
  for (int mi = 0; mi < BM / 32; ++mi)
#pragma unroll
    for (int ni = 0; ni < BN / 32; ++ni)
#pragma unroll
      for (int r = 0; r < 4; ++r) {
        int row = m0 + wm * WM + mi * 16 + lq * 4 + r;
        int col = n0 + wn * WN + ni * 16 + lm;
        C[(size_t)row * ldc + col] = acc[mi][ni][r];
      }
}

template<int BM, int BN>
__device__ __forceinline__ void write_ch(
    unsigned short* C, int ldc, int m0, int n0, f32x4 (&acc)[BM / 32][BN / 32]) {
  constexpr int WM = BM / 2, WN = BN / 2;
  int tid = threadIdx.x;
  int w = tid >> 6, l = tid & 63, lm = l & 15, lq = l >> 4;
  int wm = w >> 1, wn = w & 1;
#pragma unroll
  for (int mi = 0; mi < BM / 32; ++mi)
#pragma unroll
    for (int ni = 0; ni < BN / 32; ++ni)
#pragma unroll
      for (int r = 0; r < 4; ++r) {
        int row = m0 + wm * WM + mi * 16 + lq * 4 + r;
        int col = n0 + wn * WN + ni * 16 + lm;
        C[(size_t)row * ldc + col] = f2h(acc[mi][ni][r]);
      }
}

// qkv GEMM (fp16, 1-pass) + fused splat features.
// bx 0..7: q head bx -> qa; bx 8..15: k head bx-8 -> kw; bx 16..23: v -> vbuf (fp16).
__global__ __launch_bounds__(256) void gemm_qkv(
    const unsigned short* __restrict__ xh, const unsigned short* __restrict__ wqh,
    const float* __restrict__ cadj, const float* __restrict__ ivar,
    const float* __restrict__ ampt, unsigned short* __restrict__ vbuf,
    unsigned short* __restrict__ qa_bf, unsigned short* __restrict__ kw_bf) {
  __shared__ __align__(16) char smem[39168];
  unsigned short* ash = (unsigned short*)smem;            // 16KB
  unsigned short* bsh = (unsigned short*)(smem + 16384);  // 8KB
  int sid = swz_id();
  int bx = sid % 24, by = sid / 24;
  int m0 = by * 128;
  int tid = threadIdx.x;
  f32x4 acc[4][2];
  if (bx >= 16) {
    gemm_core<128, 64>(xh, wqh + (size_t)(1024 + (bx - 16) * 64) * 512,
                       512, m0, 0, ash, bsh, acc);
    write_ch<128, 64>(vbuf, 512, m0, (bx - 16) * 64, acc);
    return;
  }
  bool isk = bx >= 8;
  int h = bx & 7;
  gemm_core<128, 64>(xh, wqh + (size_t)((isk ? 512 : 0) + h * 64) * 512,
                     512, m0, 0, ash, bsh, acc);
  // ---- fused feature epilogue (exact fp32 q/k from accumulators) ----
  __syncthreads();                          // staging LDS dead
  float* q_s = (float*)smem;                // [128][68] = 34816B
  float* c_s = (float*)(smem + 34816);      // [16][68]  = 4352B
  {
    int w = tid >> 6, l = tid & 63, lm = l & 15, lq = l >> 4;
    int wm = w >> 1, wn = w & 1;
#pragma unroll
    for (int mi = 0; mi < 4; ++mi)
#pragma unroll
      for (int ni = 0; ni < 2; ++ni)
#pragma unroll
        for (int r = 0; r < 4; ++r)
          q_s[(wm * 64 + mi * 16 + lq * 4 + r) * 68 + wn * 32 + ni * 16 + lm] = acc[mi][ni][r];
    int cr = tid >> 4, d4 = tid & 15;
    *(float4*)&c_s[cr * 68 + d4 * 4] = *(const float4*)&cadj[(h * 16 + cr) * 64 + d4 * 4];
  }
  __syncthreads();
  int s = tid & 15, rbase = tid >> 4;
  float iv = ivar[h * 16 + s];
  float am = ampt[h * 16 + s];
  const float4* crow = (const float4*)&c_s[s * 68];
#pragma unroll
  for (int t = 0; t < 8; ++t) {
    int r = t * 16 + rbase;
    const float4* qrow = (const float4*)&q_s[r * 68];
    float d2 = 0.0f;
#pragma unroll
    for (int d4 = 0; d4 < 16; ++d4) {
      float4 qv = qrow[d4], cv = crow[d4];
      float e0 = qv.x - cv.x, e1 = qv.y - cv.y, e2 = qv.z - cv.z, e3 = qv.w - cv.w;
      d2 = fmaf(e0, e0, d2); d2 = fmaf(e1, e1, d2);
      d2 = fmaf(e2, e2, d2); d2 = fmaf(e3, e3, d2);
    }
    float val = __expf(-0.5f * d2 * iv);
    int row = m0 + r;                       // global row = b*2048 + i
    int b = row >> 11, i = row & 2047;
    size_t base = ((size_t)(b * 8 + h) * T_SEQ + i) * 32;
    if (!isk) {
      qa_bf[base + s] = f2bf(val * am);
      qa_bf[base + 16 + s] = 0;
    } else {
      int xorv = (r >> 1) & 3;
      int slot = s >> 3, e = s & 7;
      kw_bf[base + (size_t)((slot ^ xorv) << 3) + e] = f2bf(val);
      kw_bf[base + (size_t)(((2 + slot) ^ xorv) << 3) + e] = 0;
    }
  }
}

// output GEMM: fp16 aout x fp16 Wout, 64x64 tile
__global__ __launch_bounds__(256) void gemm_out(
    const unsigned short* __restrict__ aout_h, const unsigned short* __restrict__ woh,
    float* __restrict__ out) {
  __shared__ __align__(16) unsigned short ash[64 * 64];
  __shared__ __align__(16) unsigned short bsh[64 * 64];
  int sid = swz_id();
  int bx = sid % 8, by = sid / 8;
  f32x4 acc[2][2];
  gemm_core<64, 64>(aout_h + (size_t)by * 64 * 512, woh + (size_t)bx * 64 * 512,
                    512, 0, 0, ash, bsh, acc);
  write_c<64, 64>(out, 512, by * 64, bx * 64, acc);
}

// --------------------------- K3: spart[iq][bh][j] = sum_{i in quarter} (2^l - 1)
__global__ __launch_bounds__(256) void k3_colsum(
    const unsigned short* __restrict__ qa_bf, const unsigned short* __restrict__ kw_bf,
    float* __restrict__ spart) {
  int sid = swz_id();                        // grid (16, 64)
  int jblk = sid & 15, yy = sid >> 4;
  int bh = yy >> 2, iq = yy & 3;
  int tid = threadIdx.x;
  int w = tid >> 6, l = tid & 63, lm = l & 15, lq = l >> 4;
  int jbase = (jblk << 7) + (w << 5);
  int sw = lq ^ ((lm >> 1) & 3);
  size_t base32 = (size_t)bh * T_SEQ * 32;
  s16x8 kwB0 = *(const s16x8*)&kw_bf[base32 + (size_t)(jbase + lm) * 32 + sw * 8];
  s16x8 kwB1 = *(const s16x8*)&kw_bf[base32 + (size_t)(jbase + 16 + lm) * 32 + sw * 8];
  const unsigned short* qp = qa_bf + base32 + ((size_t)(iq * 512) + lm) * 32 + lq * 8;
  float s0 = 0.0f, s1 = 0.0f;
  f32x4 z = (f32x4){0.f, 0.f, 0.f, 0.f};
#pragma unroll 4
  for (int it = 0; it < 512; it += 16) {
    s16x8 qaA = *(const s16x8*)(qp + (size_t)it * 32);
    f32x4 L0 = __builtin_amdgcn_mfma_f32_16x16x32_bf16(qaA, kwB0, z, 0, 0, 0);
    f32x4 L1 = __builtin_amdgcn_mfma_f32_16x16x32_bf16(qaA, kwB1, z, 0, 0, 0);
    s0 += (fexp2(L0[0]) - 1.0f) + (fexp2(L0[1]) - 1.0f)
        + (fexp2(L0[2]) - 1.0f) + (fexp2(L0[3]) - 1.0f);
    s1 += (fexp2(L1[0]) - 1.0f) + (fexp2(L1[1]) - 1.0f)
        + (fexp2(L1[2]) - 1.0f) + (fexp2(L1[3]) - 1.0f);
  }
  s0 += __shfl_xor(s0, 16); s0 += __shfl_xor(s0, 32);
  s1 += __shfl_xor(s1, 16); s1 += __shfl_xor(s1, 32);
  if (l < 16) {
    float* sp = spart + ((size_t)iq * NBH + bh) * T_SEQ;
    sp[jbase + lm] = s0;
    sp[jbase + 16 + lm] = s1;
  }
}

// ------------- K3c: sinv inline; vt[bh][d][j_sw] = bf16(v*sinv); vpart stripes
__global__ __launch_bounds__(256) void k3c_vt(
    const unsigned short* __restrict__ vbuf, const float* __restrict__ spart,
    unsigned short* __restrict__ vt, float* __restrict__ vpart) {
  int bh = blockIdx.y; int b = bh >> 3, h = bh & 7;
  int js = blockIdx.x << 7;                  // 128 j per block
  int tid = threadIdx.x;
  __shared__ unsigned short t_s[64][136];
  __shared__ float red[16][64];
  int jg = tid >> 4, dq = tid & 15;
  const unsigned short* vb = vbuf + (size_t)b * T_SEQ * 512 + h * 64;
  const float* sp0 = spart + (size_t)bh * T_SEQ + js;
  const float* sp1 = spart + ((size_t)NBH + bh) * T_SEQ + js;
  const float* sp2 = spart + ((size_t)2 * NBH + bh) * T_SEQ + js;
  const float* sp3 = spart + ((size_t)3 * NBH + bh) * T_SEQ + js;
  float a0 = 0.f, a1 = 0.f, a2 = 0.f, a3 = 0.f;
#pragma unroll
  for (int p = 0; p < 8; ++p) {
    int j = p * 16 + jg;
    float s = 1.0f / (2048.0f + sp0[j] + sp1[j] + sp2[j] + sp3[j]);
    ushort4 vu = *(const ushort4*)&vb[(size_t)(js + j) * 512 + dq * 4];
    float v0 = h2f(vu.x) * s, v1 = h2f(vu.y) * s, v2 = h2f(vu.z) * s, v3 = h2f(vu.w) * s;
    t_s[dq * 4 + 0][j] = f2bf(v0);
    t_s[dq * 4 + 1][j] = f2bf(v1);
    t_s[dq * 4 + 2][j] = f2bf(v2);
    t_s[dq * 4 + 3][j] = f2bf(v3);
    a0 += v0; a1 += v1; a2 += v2; a3 += v3;
  }
  red[jg][dq * 4 + 0] = a0; red[jg][dq * 4 + 1] = a1;
  red[jg][dq * 4 + 2] = a2; red[jg][dq * 4 + 3] = a3;
  __syncthreads();
  if (tid < 64) {
    float t = 0.f;
#pragma unroll
    for (int g = 0; g < 16; ++g) t += red[g][tid];
    vpart[((size_t)blockIdx.x * NBH + bh) * 64 + tid] = t;
  }
#pragma unroll
  for (int p = 0; p < 4; ++p) {
    int idx = p * 256 + tid;
    int d = idx >> 4, seg = idx & 15;
    int4 val = *(const int4*)&t_s[d][seg * 8];
    int col = ((seg >> 3) << 6) + ((((seg & 7) ^ (d & 7))) << 3);
    *(int4*)&vt[(size_t)bh * 131072 + (size_t)d * 2048 + js + col] = val;
  }
}

// ------------- K4: aout = vsum + sum_j (2^l_ij - 1) * vt[j]
// 128-i blocks, 16 waves = 4 ig (32 i, 2 i-frags) x 4 jq (512 j each).
// In-register P->pA; 4-way LDS merge.
__global__ __launch_bounds__(1024) void k4_attnout(
    const unsigned short* __restrict__ qa_bf, const unsigned short* __restrict__ kw_bf,
    const unsigned short* __restrict__ vt, const float* __restrict__ vpart,
    unsigned short* __restrict__ aout_h) {
  int sid = swz_id();                        // grid (16 i-blocks, 16 bh)
  int bh = sid >> 4; int b = bh >> 3, h = bh & 7;
  int i0 = (sid & 15) << 7;                  // 128 rows per block
  int tid = threadIdx.x;
  int w = tid >> 6, l = tid & 63, lm = l & 15, lq = l >> 4;
  int ig = w >> 2, jq = w & 3;               // ig 0..3 (32 i each), jq 0..3 (512 j each)
  __shared__ __align__(16) char smem[98304];
  unsigned short* kwS = (unsigned short*)smem;             // [4][2][2048] = 32KB
  unsigned short* vtS = (unsigned short*)(smem + 32768);   // [4][2][4096] = 64KB
  float* mrg = (float*)smem;                               // 24576 f = 96KB (post-loop)
  const unsigned short* kwg = kw_bf + (size_t)bh * (T_SEQ * 32) + (size_t)jq * (512 * 32);
  const unsigned short* vtg = vt + (size_t)bh * 131072 + jq * 512;
  // kw row permutation for in-register pA
  int p0 = ((lm >> 2) << 3) | (lm & 3);
  int sw0 = lq ^ ((lm >> 1) & 1);
  int sw1 = sw0 ^ 2;
  int swv = lm & 7;
  s16x8 qaB0 = *(const s16x8*)&qa_bf[((size_t)bh * T_SEQ + i0 + ig * 32 + lm) * 32 + lq * 8];
  s16x8 qaB1 = *(const s16x8*)&qa_bf[((size_t)bh * T_SEQ + i0 + ig * 32 + 16 + lm) * 32 + lq * 8];
  f32x4 acc[2][4];
#pragma unroll
  for (int ifr = 0; ifr < 2; ++ifr)
#pragma unroll
    for (int df = 0; df < 4; ++df) acc[ifr][df] = (f32x4){0.f, 0.f, 0.f, 0.f};
  f32x4 z = (f32x4){0.f, 0.f, 0.f, 0.f};

  auto stage = [&](int c, int bsel) {
#pragma unroll
    for (int t = 0; t < 2; ++t) {
      int li = ig * 2 + t;
      gload16(&vtg[(size_t)(li * 8 + (l >> 3)) * 2048 + c * 64 + (l & 7) * 8],
              &vtS[(jq * 2 + bsel) * 4096 + li * 512]);
    }
    gload16(&kwg[(size_t)(c * 64 + ig * 16 + (l >> 2)) * 32 + (l & 3) * 8],
            &kwS[(jq * 2 + bsel) * 2048 + ig * 512]);
  };

  stage(0, 0);
  __syncthreads();
  for (int c = 0; c < 8; ++c) {
    int bsel = c & 1;
    if (c < 7) stage(c + 1, bsel ^ 1);
    const unsigned short* kwb = &kwS[(jq * 2 + bsel) * 2048];
    const unsigned short* vtb = &vtS[(jq * 2 + bsel) * 4096];
#pragma unroll
    for (int s = 0; s < 2; ++s) {
      s16x8 ka0 = *(const s16x8*)&kwb[(s * 32 + p0) * 32 + sw0 * 8];
      s16x8 ka1 = *(const s16x8*)&kwb[(s * 32 + p0 + 4) * 32 + sw1 * 8];
      s16x8 vb0 = *(const s16x8*)&vtb[(size_t)(0 + lm) * 64 + (((4 * s + lq) ^ swv) << 3)];
      s16x8 vb1 = *(const s16x8*)&vtb[(size_t)(16 + lm) * 64 + (((4 * s + lq) ^ swv) << 3)];
      s16x8 vb2 = *(const s16x8*)&vtb[(size_t)(32 + lm) * 64 + (((4 * s + lq) ^ swv) << 3)];
      s16x8 vb3 = *(const s16x8*)&vtb[(size_t)(48 + lm) * 64 + (((4 * s + lq) ^ swv) << 3)];
#pragma unroll
      for (int ifr = 0; ifr < 2; ++ifr) {
        s16x8 qaB = ifr ? qaB1 : qaB0;
        f32x4 L0 = __builtin_amdgcn_mfma_f32_16x16x32_bf16(ka0, qaB, z, 0, 0, 0);
        f32x4 L1 = __builtin_amdgcn_mfma_f32_16x16x32_bf16(ka1, qaB, z, 0, 0, 0);
        union { unsigned int u4[4]; s16x8 v; } cvt;
        cvt.u4[0] = pack2(fexp2(L0[0]) - 1.0f, fexp2(L0[1]) - 1.0f);
        cvt.u4[1] = pack2(fexp2(L0[2]) - 1.0f, fexp2(L0[3]) - 1.0f);
        cvt.u4[2] = pack2(fexp2(L1[0]) - 1.0f, fexp2(L1[1]) - 1.0f);
        cvt.u4[3] = pack2(fexp2(L1[2]) - 1.0f, fexp2(L1[3]) - 1.0f);
        s16x8 pA = cvt.v;
        __builtin_amdgcn_s_setprio(1);
        acc[ifr][0] = __builtin_amdgcn_mfma_f32_16x16x32_bf16(pA, vb0, acc[ifr][0], 0, 0, 0);
        acc[ifr][1] = __builtin_amdgcn_mfma_f32_16x16x32_bf16(pA, vb1, acc[ifr][1], 0, 0, 0);
        acc[ifr][2] = __builtin_amdgcn_mfma_f32_16x16x32_bf16(pA, vb2, acc[ifr][2], 0, 0, 0);
        acc[ifr][3] = __builtin_amdgcn_mfma_f32_16x16x32_bf16(pA, vb3, acc[ifr][3], 0, 0, 0);
        __builtin_amdgcn_s_setprio(0);
      }
    }
    __syncthreads();
  }
  // 4-way merge across jq via LDS (reuse full 96KB smem), jq=0 waves write out
  if (jq != 0) {
    int base = ((jq - 1) * 4 + ig) * 2;
#pragma unroll
    for (int ifr = 0; ifr < 2; ++ifr)
#pragma unroll
      for (int df = 0; df < 4; ++df)
#pragma unroll
        for (int r = 0; r < 4; ++r)
          mrg[(((base + ifr) * 4 + df) * 4 + r) * 64 + l] = acc[ifr][df][r];
  }
  __syncthreads();
  if (jq == 0) {
#pragma unroll
    for (int ifr = 0; ifr < 2; ++ifr)
#pragma unroll
      for (int df = 0; df < 4; ++df) {
        int d = df * 16 + lm;
        float vs = 0.0f;
#pragma unroll
        for (int js = 0; js < 16; ++js) vs += vpart[((size_t)js * NBH + bh) * 64 + d];
#pragma unroll
        for (int r = 0; r < 4; ++r) {
          int row = i0 + ig * 32 + ifr * 16 + lq * 4 + r;
          float o = acc[ifr][df][r] + vs;
#pragma unroll
          for (int jm = 0; jm < 3; ++jm)
            o += mrg[((((jm * 4 + ig) * 2 + ifr) * 4 + df) * 4 + r) * 64 + l];
          aout_h[((size_t)b * T_SEQ + row) * DIMD + h * 64 + d] = f2h(o);
        }
      }
  }
}

// ----------------------------------------------------------------------------
extern "C" void kernel_launch(void* const* d_in, const int* in_sizes, int n_in,
                              void* d_out, int out_size, void* d_ws, size_t ws_size,
                              hipStream_t stream) {
  const float* x    = (const float*)d_in[0];
  const float* Wqkv = (const float*)d_in[1];
  const float* Wout = (const float*)d_in[2];
  const float* ctr  = (const float*)d_in[3];
  const float* dlt  = (const float*)d_in[4];
  const float* lsc  = (const float*)d_in[5];
  const float* lam  = (const float*)d_in[6];
  const float* ms   = (const float*)d_in[7];
  const float* tp   = (const float*)d_in[8];
  float* ws = (float*)d_ws;
  unsigned short* vbuf   = (unsigned short*)(ws + OFF_VBUF);   // fp16
  unsigned short* aout_h = (unsigned short*)(ws + OFF_AOUT);   // fp16
  unsigned short* xh  = (unsigned short*)(ws + OFF_XH);        // fp16
  unsigned short* wqh = (unsigned short*)(ws + OFF_WQH);       // fp16
  unsigned short* woh = (unsigned short*)(ws + OFF_WOH);       // fp16
  unsigned short* qa_bf = (unsigned short*)(ws + OFF_QABF);
  unsigned short* kw_bf = (unsigned short*)(ws + OFF_KWBF);
  float* spart = ws + OFF_SPART;
  float* vpart = ws + OFF_VPART;
  float* cadj  = ws + OFF_CADJ;
  float* ivar  = ws + OFF_IVAR;
  float* ampt  = ws + OFF_AMPT;
  unsigned short* vt = xh;                 // bf16 vt aliases xh (dead after gemm_qkv)
  float* out = (float*)d_out;

  prep<<<3073, 256, 0, stream>>>(x, Wqkv, Wout, ctr, dlt, lsc, lam, ms, tp,
                                 xh, wqh, woh, cadj, ivar, ampt);
  gemm_qkv<<<dim3(24, 32), 256, 0, stream>>>(xh, wqh, cadj, ivar, ampt,
                                             vbuf, qa_bf, kw_bf);
  k3_colsum<<<dim3(16, 64), 256, 0, stream>>>(qa_bf, kw_bf, spart);
  k3c_vt<<<dim3(16, 16), 256, 0, stream>>>(vbuf, spart, vt, vpart);
  k4_attnout<<<dim3(16, 16), 1024, 0, stream>>>(qa_bf, kw_bf, vt, vpart, aout_h);
  gemm_out<<<dim3(8, 64), 256, 0, stream>>>(aout_h, woh, out);
}

// Round 19
// 73.042 us; speedup vs baseline: 1.2269x; 1.0313x over previous
//
#include <hip/hip_runtime.h>
#include <hip/hip_bf16.h>
#include <hip/hip_fp16.h>
#include <cstdint>
#include <cstddef>

#define T_SEQ 2048
#define NBATCH 2
#define DIMD 512
#define NH 8
#define NS 16
#define HD 64
#define NBH 16

using s16x8 = __attribute__((ext_vector_type(8))) short;
using f32x4 = __attribute__((ext_vector_type(4))) float;

static __device__ inline unsigned short f2bf(float f) {
  __hip_bfloat16 h = __float2bfloat16(f);
  return reinterpret_cast<unsigned short&>(h);
}
static __device__ inline unsigned short f2h(float f) {
  __half h = __float2half(f);
  return reinterpret_cast<unsigned short&>(h);
}
static __device__ inline float h2f(unsigned short u) {
  __half h = reinterpret_cast<__half&>(u);
  return __half2float(h);
}
static __device__ inline unsigned int pack2(float a, float b) {
  return (unsigned int)f2bf(a) | ((unsigned int)f2bf(b) << 16);
}
static __device__ inline float fexp2(float x) {
  return __builtin_amdgcn_exp2f(x);          // bare v_exp_f32 (2^x)
}
static __device__ inline void gload16(const void* g, void* l) {
  __builtin_amdgcn_global_load_lds((const __attribute__((address_space(1))) void*)g,
                                   (__attribute__((address_space(3))) void*)l, 16, 0, 0);
}
// bijective XCD swizzle (nwg % 8 == 0)
static __device__ inline int swz_id() {
  int nwg = gridDim.x * gridDim.y;
  int orig = blockIdx.y * gridDim.x + blockIdx.x;
  return (orig & 7) * (nwg >> 3) + (orig >> 3);
}

// ---- workspace layout (float offsets) ----
static const size_t OFF_VBUF = 0;         // 4096x512 fp16 v
static const size_t OFF_AOUT = 2097152;   // 4096x512 fp16 attn-out
static const size_t OFF_XH   = 6291456;   // fp16 x (4MB); later aliased by vt (bf16 4MB)
static const size_t OFF_WQH  = 8388608;   // fp16 Wqkv
static const size_t OFF_WOH  = 9175040;   // fp16 Wout
static const size_t OFF_QABF = 9437184;   // 16x2048x32 bf16, PLAIN layout
static const size_t OFF_KWBF = 9961472;   // 16x2048x32 bf16, slot-swizzled
static const size_t OFF_SPART= 10485760;  // [4][16][2048] f32 partial colsums
static const size_t OFF_VPART= 10616832;  // [16][16][64] f32
static const size_t OFF_CADJ = 10633216;
static const size_t OFF_IVAR = 10641408;
static const size_t OFF_AMPT = 10641536;

// ------------------- PREP: params + fp32->fp16 conversions
__global__ __launch_bounds__(256) void prep(
    const float* __restrict__ x, const float* __restrict__ Wqkv, const float* __restrict__ Wout,
    const float* __restrict__ centers, const float* __restrict__ deltas,
    const float* __restrict__ lsc, const float* __restrict__ lam,
    const float* __restrict__ ms, const float* __restrict__ tp,
    unsigned short* __restrict__ xh, unsigned short* __restrict__ wqh,
    unsigned short* __restrict__ woh,
    float* __restrict__ cadj, float* __restrict__ ivar, float* __restrict__ ampt) {
  int bid = blockIdx.x;
  int tid = threadIdx.x;
  if (bid == 3072) {
    float bscale = 0.2f / (1.0f + expf(-ms[0]));
    float tclip = fminf(fmaxf(tp[0], 0.1f), 10.0f);
    if (tid < NH * NS) {
      float sc = fminf(fmaxf(expf(lsc[tid]), 0.01f), 2.0f);
      ivar[tid] = 1.0f / (sc * sc + 1e-8f);
      float am = fminf(fmaxf(expf(lam[tid]), 1e-6f), 10.0f);
      am = (am > 0.02f) ? am : 0.0f;
      // fold 1/temp AND log2(e) into qa so logits feed v_exp_f32 (2^x) directly
      ampt[tid] = (am / tclip) * 1.44269504088896340736f;
    }
    for (int e = tid; e < NH * NS * HD; e += 256)
      cadj[e] = centers[e] + deltas[e] * bscale;
    return;
  }
  const float* src; unsigned short* dh; int i4;
  if (bid < 2048)      { src = x;    dh = xh;  i4 = bid * 256 + tid; }
  else if (bid < 2816) { src = Wqkv; dh = wqh; i4 = (bid - 2048) * 256 + tid; }
  else                 { src = Wout; dh = woh; i4 = (bid - 2816) * 256 + tid; }
  float4 v = *(const float4*)&src[(size_t)i4 * 4];
  ushort4 hh;
  hh.x = f2h(v.x); hh.y = f2h(v.y); hh.z = f2h(v.z); hh.w = f2h(v.w);
  *(ushort4*)&dh[(size_t)i4 * 4] = hh;
}

// ---- fp16 1-pass MFMA GEMM core, BK=64, swizzled LDS rows; acc in registers
template<int BM, int BN>
__device__ __forceinline__ void gemm_core(
    const unsigned short* Ah, const unsigned short* Bh,
    int K, int m0, int n0,
    unsigned short* ash, unsigned short* bsh,
    f32x4 (&acc)[BM / 32][BN / 32]) {
  constexpr int WM = BM / 2, WN = BN / 2;
  constexpr int MF = WM / 16, NF = WN / 16;
  constexpr int NSA = BM / 8, NSB = BN / 8;
  constexpr int TSEG = NSA + NSB;
  int tid = threadIdx.x;
  int w = tid >> 6, l = tid & 63, lm = l & 15, lq = l >> 4;
  int wm = w >> 1, wn = w & 1;
  int r8 = l >> 3, c8 = l & 7;
  int ksl = (c8 ^ (r8 & 7)) << 3;
#pragma unroll
  for (int mi = 0; mi < MF; ++mi)
#pragma unroll
    for (int ni = 0; ni < NF; ++ni) acc[mi][ni] = (f32x4){0.f, 0.f, 0.f, 0.f};

  for (int k0 = 0; k0 < K; k0 += 64) {
    __syncthreads();
#pragma unroll
    for (int t = 0; t < TSEG / 4; ++t) {
      int s = w + t * 4;
      if (s < NSA) {
        gload16(&Ah[(size_t)(m0 + s * 8 + r8) * K + k0 + ksl], &ash[s * 512]);
      } else {
        int ss = s - NSA;
        gload16(&Bh[(size_t)(n0 + ss * 8 + r8) * K + k0 + ksl], &bsh[ss * 512]);
      }
    }
    __syncthreads();
#pragma unroll
    for (int kh = 0; kh < 2; ++kh) {
      s16x8 fah[MF], fbh[NF];
#pragma unroll
      for (int mi = 0; mi < MF; ++mi) {
        int rr = wm * WM + mi * 16 + lm;
        int off = rr * 64 + ((((kh << 2) | lq) ^ (rr & 7)) << 3);
        fah[mi] = *(const s16x8*)&ash[off];
      }
#pragma unroll
      for (int ni = 0; ni < NF; ++ni) {
        int cc = wn * WN + ni * 16 + lm;
        int off = cc * 64 + ((((kh << 2) | lq) ^ (cc & 7)) << 3);
        fbh[ni] = *(const s16x8*)&bsh[off];
      }
#pragma unroll
      for (int mi = 0; mi < MF; ++mi)
#pragma unroll
        for (int ni = 0; ni < NF; ++ni)
          acc[mi][ni] = __builtin_amdgcn_mfma_f32_16x16x32_f16(fah[mi], fbh[ni], acc[mi][ni], 0, 0, 0);
    }
  }
}

template<int BM, int BN>
__device__ __forceinline__ void write_c(
    float* C, int ldc, int m0, int n0, f32x4 (&acc)[BM / 32][BN / 32]) {
  constexpr int WM = BM / 2, WN = BN / 2;
  int tid = threadIdx.x;
  int w = tid >> 6, l = tid & 63, lm = l & 15, lq = l >> 4;
  int wm = w >> 1, wn = w & 1;
#pragma unroll
  for (int mi = 0; mi < BM / 32; ++mi)
#pragma unroll
    for (int ni = 0; ni < BN / 32; ++ni)
#pragma unroll
      for (int r = 0; r < 4; ++r) {
        int row = m0 + wm * WM + mi * 16 + lq * 4 + r;
        int col = n0 + wn * WN + ni * 16 + lm;
        C[(size_t)row * ldc + col] = acc[mi][ni][r];
      }
}

template<int BM, int BN>
__device__ __forceinline__ void write_ch(
    unsigned short* C, int ldc, int m0, int n0, f32x4 (&acc)[BM / 32][BN / 32]) {
  constexpr int WM = BM / 2, WN = BN / 2;
  int tid = threadIdx.x;
  int w = tid >> 6, l = tid & 63, lm = l & 15, lq = l >> 4;
  int wm = w >> 1, wn = w & 1;
#pragma unroll
  for (int mi = 0; mi < BM / 32; ++mi)
#pragma unroll
    for (int ni = 0; ni < BN / 32; ++ni)
#pragma unroll
      for (int r = 0; r < 4; ++r) {
        int row = m0 + wm * WM + mi * 16 + lq * 4 + r;
        int col = n0 + wn * WN + ni * 16 + lm;
        C[(size_t)row * ldc + col] = f2h(acc[mi][ni][r]);
      }
}

// qkv GEMM (fp16, 1-pass) + fused splat features.
// bx 0..7: q head bx -> qa; bx 8..15: k head bx-8 -> kw; bx 16..23: v -> vbuf (fp16).
__global__ __launch_bounds__(256) void gemm_qkv(
    const unsigned short* __restrict__ xh, const unsigned short* __restrict__ wqh,
    const float* __restrict__ cadj, const float* __restrict__ ivar,
    const float* __restrict__ ampt, unsigned short* __restrict__ vbuf,
    unsigned short* __restrict__ qa_bf, unsigned short* __restrict__ kw_bf) {
  __shared__ __align__(16) char smem[39168];
  unsigned short* ash = (unsigned short*)smem;            // 16KB
  unsigned short* bsh = (unsigned short*)(smem + 16384);  // 8KB
  int sid = swz_id();
  int bx = sid % 24, by = sid / 24;
  int m0 = by * 128;
  int tid = threadIdx.x;
  f32x4 acc[4][2];
  if (bx >= 16) {
    gemm_core<128, 64>(xh, wqh + (size_t)(1024 + (bx - 16) * 64) * 512,
                       512, m0, 0, ash, bsh, acc);
    write_ch<128, 64>(vbuf, 512, m0, (bx - 16) * 64, acc);
    return;
  }
  bool isk = bx >= 8;
  int h = bx & 7;
  gemm_core<128, 64>(xh, wqh + (size_t)((isk ? 512 : 0) + h * 64) * 512,
                     512, m0, 0, ash, bsh, acc);
  // ---- fused feature epilogue (exact fp32 q/k from accumulators) ----
  __syncthreads();                          // staging LDS dead
  float* q_s = (float*)smem;                // [128][68] = 34816B
  float* c_s = (float*)(smem + 34816);      // [16][68]  = 4352B
  {
    int w = tid >> 6, l = tid & 63, lm = l & 15, lq = l >> 4;
    int wm = w >> 1, wn = w & 1;
#pragma unroll
    for (int mi = 0; mi < 4; ++mi)
#pragma unroll
      for (int ni = 0; ni < 2; ++ni)
#pragma unroll
        for (int r = 0; r < 4; ++r)
          q_s[(wm * 64 + mi * 16 + lq * 4 + r) * 68 + wn * 32 + ni * 16 + lm] = acc[mi][ni][r];
    int cr = tid >> 4, d4 = tid & 15;
    *(float4*)&c_s[cr * 68 + d4 * 4] = *(const float4*)&cadj[(h * 16 + cr) * 64 + d4 * 4];
  }
  __syncthreads();
  int s = tid & 15, rbase = tid >> 4;
  float iv = ivar[h * 16 + s];
  float am = ampt[h * 16 + s];
  const float4* crow = (const float4*)&c_s[s * 68];
#pragma unroll
  for (int t = 0; t < 8; ++t) {
    int r = t * 16 + rbase;
    const float4* qrow = (const float4*)&q_s[r * 68];
    float d2 = 0.0f;
#pragma unroll
    for (int d4 = 0; d4 < 16; ++d4) {
      float4 qv = qrow[d4], cv = crow[d4];
      float e0 = qv.x - cv.x, e1 = qv.y - cv.y, e2 = qv.z - cv.z, e3 = qv.w - cv.w;
      d2 = fmaf(e0, e0, d2); d2 = fmaf(e1, e1, d2);
      d2 = fmaf(e2, e2, d2); d2 = fmaf(e3, e3, d2);
    }
    float val = __expf(-0.5f * d2 * iv);
    int row = m0 + r;                       // global row = b*2048 + i
    int b = row >> 11, i = row & 2047;
    size_t base = ((size_t)(b * 8 + h) * T_SEQ + i) * 32;
    if (!isk) {
      qa_bf[base + s] = f2bf(val * am);
      qa_bf[base + 16 + s] = 0;
    } else {
      int xorv = (r >> 1) & 3;
      int slot = s >> 3, e = s & 7;
      kw_bf[base + (size_t)((slot ^ xorv) << 3) + e] = f2bf(val);
      kw_bf[base + (size_t)(((2 + slot) ^ xorv) << 3) + e] = 0;
    }
  }
}

// output GEMM: fp16 aout x fp16 Wout, 64x64 tile
__global__ __launch_bounds__(256) void gemm_out(
    const unsigned short* __restrict__ aout_h, const unsigned short* __restrict__ woh,
    float* __restrict__ out) {
  __shared__ __align__(16) unsigned short ash[64 * 64];
  __shared__ __align__(16) unsigned short bsh[64 * 64];
  int sid = swz_id();
  int bx = sid % 8, by = sid / 8;
  f32x4 acc[2][2];
  gemm_core<64, 64>(aout_h + (size_t)by * 64 * 512, woh + (size_t)bx * 64 * 512,
                    512, 0, 0, ash, bsh, acc);
  write_c<64, 64>(out, 512, by * 64, bx * 64, acc);
}

// --------------------------- K3: spart[iq][bh][j] = sum_{i in quarter} 2^l_ij
__global__ __launch_bounds__(256) void k3_colsum(
    const unsigned short* __restrict__ qa_bf, const unsigned short* __restrict__ kw_bf,
    float* __restrict__ spart) {
  int sid = swz_id();                        // grid (16, 64)
  int jblk = sid & 15, yy = sid >> 4;
  int bh = yy >> 2, iq = yy & 3;
  int tid = threadIdx.x;
  int w = tid >> 6, l = tid & 63, lm = l & 15, lq = l >> 4;
  int jbase = (jblk << 7) + (w << 5);
  int sw = lq ^ ((lm >> 1) & 3);
  size_t base32 = (size_t)bh * T_SEQ * 32;
  s16x8 kwB0 = *(const s16x8*)&kw_bf[base32 + (size_t)(jbase + lm) * 32 + sw * 8];
  s16x8 kwB1 = *(const s16x8*)&kw_bf[base32 + (size_t)(jbase + 16 + lm) * 32 + sw * 8];
  const unsigned short* qp = qa_bf + base32 + ((size_t)(iq * 512) + lm) * 32 + lq * 8;
  float s0 = 0.0f, s1 = 0.0f;
  f32x4 z = (f32x4){0.f, 0.f, 0.f, 0.f};
#pragma unroll 4
  for (int it = 0; it < 512; it += 16) {
    s16x8 qaA = *(const s16x8*)(qp + (size_t)it * 32);
    f32x4 L0 = __builtin_amdgcn_mfma_f32_16x16x32_bf16(qaA, kwB0, z, 0, 0, 0);
    f32x4 L1 = __builtin_amdgcn_mfma_f32_16x16x32_bf16(qaA, kwB1, z, 0, 0, 0);
    s0 += fexp2(L0[0]) + fexp2(L0[1]) + fexp2(L0[2]) + fexp2(L0[3]);
    s1 += fexp2(L1[0]) + fexp2(L1[1]) + fexp2(L1[2]) + fexp2(L1[3]);
  }
  s0 += __shfl_xor(s0, 16); s0 += __shfl_xor(s0, 32);
  s1 += __shfl_xor(s1, 16); s1 += __shfl_xor(s1, 32);
  if (l < 16) {
    float* sp = spart + ((size_t)iq * NBH + bh) * T_SEQ;
    sp[jbase + lm] = s0;
    sp[jbase + 16 + lm] = s1;
  }
}

// ------------- K3c: sinv inline (1/sum of exp); vt = bf16(v*sinv); vpart stripes
__global__ __launch_bounds__(256) void k3c_vt(
    const unsigned short* __restrict__ vbuf, const float* __restrict__ spart,
    unsigned short* __restrict__ vt, float* __restrict__ vpart) {
  int bh = blockIdx.y; int b = bh >> 3, h = bh & 7;
  int js = blockIdx.x << 7;                  // 128 j per block
  int tid = threadIdx.x;
  __shared__ unsigned short t_s[64][136];
  __shared__ float red[16][64];
  int jg = tid >> 4, dq = tid & 15;
  const unsigned short* vb = vbuf + (size_t)b * T_SEQ * 512 + h * 64;
  const float* sp0 = spart + (size_t)bh * T_SEQ + js;
  const float* sp1 = spart + ((size_t)NBH + bh) * T_SEQ + js;
  const float* sp2 = spart + ((size_t)2 * NBH + bh) * T_SEQ + js;
  const float* sp3 = spart + ((size_t)3 * NBH + bh) * T_SEQ + js;
  float a0 = 0.f, a1 = 0.f, a2 = 0.f, a3 = 0.f;
#pragma unroll
  for (int p = 0; p < 8; ++p) {
    int j = p * 16 + jg;
    float s = 1.0f / (sp0[j] + sp1[j] + sp2[j] + sp3[j]);
    ushort4 vu = *(const ushort4*)&vb[(size_t)(js + j) * 512 + dq * 4];
    float v0 = h2f(vu.x) * s, v1 = h2f(vu.y) * s, v2 = h2f(vu.z) * s, v3 = h2f(vu.w) * s;
    t_s[dq * 4 + 0][j] = f2bf(v0);
    t_s[dq * 4 + 1][j] = f2bf(v1);
    t_s[dq * 4 + 2][j] = f2bf(v2);
    t_s[dq * 4 + 3][j] = f2bf(v3);
    a0 += v0; a1 += v1; a2 += v2; a3 += v3;
  }
  red[jg][dq * 4 + 0] = a0; red[jg][dq * 4 + 1] = a1;
  red[jg][dq * 4 + 2] = a2; red[jg][dq * 4 + 3] = a3;
  __syncthreads();
  if (tid < 64) {
    float t = 0.f;
#pragma unroll
    for (int g = 0; g < 16; ++g) t += red[g][tid];
    vpart[((size_t)blockIdx.x * NBH + bh) * 64 + tid] = t;
  }
#pragma unroll
  for (int p = 0; p < 4; ++p) {
    int idx = p * 256 + tid;
    int d = idx >> 4, seg = idx & 15;
    int4 val = *(const int4*)&t_s[d][seg * 8];
    int col = ((seg >> 3) << 6) + ((((seg & 7) ^ (d & 7))) << 3);
    *(int4*)&vt[(size_t)bh * 131072 + (size_t)d * 2048 + js + col] = val;
  }
}

// ------------- K4: aout = vsum + sum_j (2^l_ij - 1) * vt[j]
// 128-i blocks, 16 waves = 4 ig (32 i, 2 i-frags) x 4 jq (512 j each).
// In-register P->pA; 4-way LDS merge; vpart hoisted to prologue.
__global__ __launch_bounds__(1024) void k4_attnout(
    const unsigned short* __restrict__ qa_bf, const unsigned short* __restrict__ kw_bf,
    const unsigned short* __restrict__ vt, const float* __restrict__ vpart,
    unsigned short* __restrict__ aout_h) {
  int sid = swz_id();                        // grid (16 i-blocks, 16 bh)
  int bh = sid >> 4; int b = bh >> 3, h = bh & 7;
  int i0 = (sid & 15) << 7;                  // 128 rows per block
  int tid = threadIdx.x;
  int w = tid >> 6, l = tid & 63, lm = l & 15, lq = l >> 4;
  int ig = w >> 2, jq = w & 3;               // ig 0..3 (32 i each), jq 0..3 (512 j each)
  __shared__ __align__(16) char smem[98304];
  unsigned short* kwS = (unsigned short*)smem;             // [4][2][2048] = 32KB
  unsigned short* vtS = (unsigned short*)(smem + 32768);   // [4][2][4096] = 64KB
  float* mrg = (float*)smem;                               // 24576 f = 96KB (post-loop)
  const unsigned short* kwg = kw_bf + (size_t)bh * (T_SEQ * 32) + (size_t)jq * (512 * 32);
  const unsigned short* vtg = vt + (size_t)bh * 131072 + jq * 512;
  // vpart sums hoisted: only jq==0 waves need them; loads hide under the K loop
  float vs4[4] = {0.f, 0.f, 0.f, 0.f};
  if (jq == 0) {
#pragma unroll
    for (int df = 0; df < 4; ++df) {
      int d = df * 16 + lm;
      float vs = 0.0f;
#pragma unroll
      for (int js = 0; js < 16; ++js) vs += vpart[((size_t)js * NBH + bh) * 64 + d];
      vs4[df] = vs;
    }
  }
  // kw row permutation for in-register pA
  int p0 = ((lm >> 2) << 3) | (lm & 3);
  int sw0 = lq ^ ((lm >> 1) & 1);
  int sw1 = sw0 ^ 2;
  int swv = lm & 7;
  s16x8 qaB0 = *(const s16x8*)&qa_bf[((size_t)bh * T_SEQ + i0 + ig * 32 + lm) * 32 + lq * 8];
  s16x8 qaB1 = *(const s16x8*)&qa_bf[((size_t)bh * T_SEQ + i0 + ig * 32 + 16 + lm) * 32 + lq * 8];
  f32x4 acc[2][4];
#pragma unroll
  for (int ifr = 0; ifr < 2; ++ifr)
#pragma unroll
    for (int df = 0; df < 4; ++df) acc[ifr][df] = (f32x4){0.f, 0.f, 0.f, 0.f};
  f32x4 z = (f32x4){0.f, 0.f, 0.f, 0.f};

  auto stage = [&](int c, int bsel) {
#pragma unroll
    for (int t = 0; t < 2; ++t) {
      int li = ig * 2 + t;
      gload16(&vtg[(size_t)(li * 8 + (l >> 3)) * 2048 + c * 64 + (l & 7) * 8],
              &vtS[(jq * 2 + bsel) * 4096 + li * 512]);
    }
    gload16(&kwg[(size_t)(c * 64 + ig * 16 + (l >> 2)) * 32 + (l & 3) * 8],
            &kwS[(jq * 2 + bsel) * 2048 + ig * 512]);
  };

  stage(0, 0);
  __syncthreads();
  for (int c = 0; c < 8; ++c) {
    int bsel = c & 1;
    if (c < 7) stage(c + 1, bsel ^ 1);
    const unsigned short* kwb = &kwS[(jq * 2 + bsel) * 2048];
    const unsigned short* vtb = &vtS[(jq * 2 + bsel) * 4096];
#pragma unroll
    for (int s = 0; s < 2; ++s) {
      s16x8 ka0 = *(const s16x8*)&kwb[(s * 32 + p0) * 32 + sw0 * 8];
      s16x8 ka1 = *(const s16x8*)&kwb[(s * 32 + p0 + 4) * 32 + sw1 * 8];
      s16x8 vb0 = *(const s16x8*)&vtb[(size_t)(0 + lm) * 64 + (((4 * s + lq) ^ swv) << 3)];
      s16x8 vb1 = *(const s16x8*)&vtb[(size_t)(16 + lm) * 64 + (((4 * s + lq) ^ swv) << 3)];
      s16x8 vb2 = *(const s16x8*)&vtb[(size_t)(32 + lm) * 64 + (((4 * s + lq) ^ swv) << 3)];
      s16x8 vb3 = *(const s16x8*)&vtb[(size_t)(48 + lm) * 64 + (((4 * s + lq) ^ swv) << 3)];
#pragma unroll
      for (int ifr = 0; ifr < 2; ++ifr) {
        s16x8 qaB = ifr ? qaB1 : qaB0;
        f32x4 L0 = __builtin_amdgcn_mfma_f32_16x16x32_bf16(ka0, qaB, z, 0, 0, 0);
        f32x4 L1 = __builtin_amdgcn_mfma_f32_16x16x32_bf16(ka1, qaB, z, 0, 0, 0);
        union { unsigned int u4[4]; s16x8 v; } cvt;
        cvt.u4[0] = pack2(fexp2(L0[0]) - 1.0f, fexp2(L0[1]) - 1.0f);
        cvt.u4[1] = pack2(fexp2(L0[2]) - 1.0f, fexp2(L0[3]) - 1.0f);
        cvt.u4[2] = pack2(fexp2(L1[0]) - 1.0f, fexp2(L1[1]) - 1.0f);
        cvt.u4[3] = pack2(fexp2(L1[2]) - 1.0f, fexp2(L1[3]) - 1.0f);
        s16x8 pA = cvt.v;
        __builtin_amdgcn_s_setprio(1);
        acc[ifr][0] = __builtin_amdgcn_mfma_f32_16x16x32_bf16(pA, vb0, acc[ifr][0], 0, 0, 0);
        acc[ifr][1] = __builtin_amdgcn_mfma_f32_16x16x32_bf16(pA, vb1, acc[ifr][1], 0, 0, 0);
        acc[ifr][2] = __builtin_amdgcn_mfma_f32_16x16x32_bf16(pA, vb2, acc[ifr][2], 0, 0, 0);
        acc[ifr][3] = __builtin_amdgcn_mfma_f32_16x16x32_bf16(pA, vb3, acc[ifr][3], 0, 0, 0);
        __builtin_amdgcn_s_setprio(0);
      }
    }
    __syncthreads();
  }
  // 4-way merge across jq via LDS (reuse full 96KB smem), jq=0 waves write out
  if (jq != 0) {
    int base = ((jq - 1) * 4 + ig) * 2;
#pragma unroll
    for (int ifr = 0; ifr < 2; ++ifr)
#pragma unroll
      for (int df = 0; df < 4; ++df)
#pragma unroll
        for (int r = 0; r < 4; ++r)
          mrg[(((base + ifr) * 4 + df) * 4 + r) * 64 + l] = acc[ifr][df][r];
  }
  __syncthreads();
  if (jq == 0) {
#pragma unroll
    for (int ifr = 0; ifr < 2; ++ifr)
#pragma unroll
      for (int df = 0; df < 4; ++df) {
#pragma unroll
        for (int r = 0; r < 4; ++r) {
          int row = i0 + ig * 32 + ifr * 16 + lq * 4 + r;
          float o = acc[ifr][df][r] + vs4[df];
#pragma unroll
          for (int jm = 0; jm < 3; ++jm)
            o += mrg[((((jm * 4 + ig) * 2 + ifr) * 4 + df) * 4 + r) * 64 + l];
          aout_h[((size_t)b * T_SEQ + row) * DIMD + h * 64 + df * 16 + lm] = f2h(o);
        }
      }
  }
}

// ----------------------------------------------------------------------------
extern "C" void kernel_launch(void* const* d_in, const int* in_sizes, int n_in,
                              void* d_out, int out_size, void* d_ws, size_t ws_size,
                              hipStream_t stream) {
  const float* x    = (const float*)d_in[0];
  const float* Wqkv = (const float*)d_in[1];
  const float* Wout = (const float*)d_in[2];
  const float* ctr  = (const float*)d_in[3];
  const float* dlt  = (const float*)d_in[4];
  const float* lsc  = (const float*)d_in[5];
  const float* lam  = (const float*)d_in[6];
  const float* ms   = (const float*)d_in[7];
  const float* tp   = (const float*)d_in[8];
  float* ws = (float*)d_ws;
  unsigned short* vbuf   = (unsigned short*)(ws + OFF_VBUF);   // fp16
  unsigned short* aout_h = (unsigned short*)(ws + OFF_AOUT);   // fp16
  unsigned short* xh  = (unsigned short*)(ws + OFF_XH);        // fp16
  unsigned short* wqh = (unsigned short*)(ws + OFF_WQH);       // fp16
  unsigned short* woh = (unsigned short*)(ws + OFF_WOH);       // fp16
  unsigned short* qa_bf = (unsigned short*)(ws + OFF_QABF);
  unsigned short* kw_bf = (unsigned short*)(ws + OFF_KWBF);
  float* spart = ws + OFF_SPART;
  float* vpart = ws + OFF_VPART;
  float* cadj  = ws + OFF_CADJ;
  float* ivar  = ws + OFF_IVAR;
  float* ampt  = ws + OFF_AMPT;
  unsigned short* vt = xh;                 // bf16 vt aliases xh (dead after gemm_qkv)
  float* out = (float*)d_out;

  prep<<<3073, 256, 0, stream>>>(x, Wqkv, Wout, ctr, dlt, lsc, lam, ms, tp,
                                 xh, wqh, woh, cadj, ivar, ampt);
  gemm_qkv<<<dim3(24, 32), 256, 0, stream>>>(xh, wqh, cadj, ivar, ampt,
                                             vbuf, qa_bf, kw_bf);
  k3_colsum<<<dim3(16, 64), 256, 0, stream>>>(qa_bf, kw_bf, spart);
  k3c_vt<<<dim3(16, 16), 256, 0, stream>>>(vbuf, spart, vt, vpart);
  k4_attnout<<<dim3(16, 16), 1024, 0, stream>>>(qa_bf, kw_bf, vt, vpart, aout_h);
  gemm_out<<<dim3(8, 64), 256, 0, stream>>>(aout_h, woh, out);
}